// Round 6
// baseline (321.594 us; speedup 1.0000x reference)
//
#include <hip/hip_runtime.h>

// FnRGNN: 2-layer GCN w/ cosine-sim edge weights. f32 math, f32 output
// [y(N), h(N*128)]. Inputs runtime-classified (f32/bf16, i64/i32).
// R18: aggemm occupancy doubled (R17 was wave-starved: 782 blocks x 4 waves
// = 12.2 waves/CU, vs ewcsr's 73% occ at same gather volume). 512-thread
// blocks, 8 waves; each 16-row tile owned by a WAVE PAIR splitting its CSR
// range at the midpoint; both halves flush into shared Acc[tile] via LDS
// float atomicAdds (row-flush only, ~17/half-wave, ds_add_f32). Odd-wave
// cursor init via ballot/popcount over shfl'd row bounds. Phase 2: pair
// splits 8 column-tiles 4/4 (disjoint h cols); y partials merged via 256B
// LDS ybuf + barrier. LDS 34KB -> 4 blk/CU -> 32 waves/CU available (24.4
// needed, fully resident). Bucket-level hist (R15), two-level bucket
// scatter (R14), ewcsr CSR-order weights w/ fused dinv (R13). MFMA gemm w/
// prepacked B-fragments (identity-proven layouts). CSR rec = (src<<16)|
// bf16(w) packed 4B (N<=65536). Agg-first GCN form. ws ~= 16.9 MB.

typedef unsigned short u16;
typedef unsigned int u32;
typedef __attribute__((ext_vector_type(8))) short short8;
typedef __attribute__((ext_vector_type(4))) float floatx4;

__device__ __forceinline__ float bflo(u32 u){ return __uint_as_float(u << 16); }
__device__ __forceinline__ float bfhi(u32 u){ return __uint_as_float(u & 0xFFFF0000u); }
__device__ __forceinline__ float bf1(u16 u){ return __uint_as_float(((u32)u) << 16); }
__device__ __forceinline__ u16 f2bf(float f){
    u32 u = __float_as_uint(f);
    u += 0x7FFFu + ((u >> 16) & 1u);   // RNE
    return (u16)(u >> 16);
}
__device__ __forceinline__ u32 pack2(float a, float b){
    return (u32)f2bf(a) | ((u32)f2bf(b) << 16);
}
__device__ __forceinline__ float wsum(float v){
#pragma unroll
    for (int o = 32; o > 0; o >>= 1) v += __shfl_xor(v, o, 64);
    return v;
}
__device__ __forceinline__ float ld1(const void* p, size_t idx, int f32){
    return f32 ? ((const float*)p)[idx] : bf1(((const u16*)p)[idx]);
}
__device__ __forceinline__ int ldidx(const int* p, size_t i, int i64){
    return i64 ? p[2 * i] : p[i];   // int64 low word
}

// ---- classify: flags[0]=reals are f32, flags[1]=ints are i64; zero bcnt -----
__global__ void classify_k(const u32* __restrict__ xw, const int* __restrict__ eiw,
                           int* __restrict__ flags, int* __restrict__ bcnt)
{
    __shared__ int c_out, c_nz;
    int t = threadIdx.x;
    if (t == 0) { c_out = 0; c_nz = 0; }
    if (t < 256) bcnt[t] = 0;
    __syncthreads();
    u32 w = xw[t];
    int e = (w >> 7) & 0xFF;
    int outl = (e < 110 || e > 140) ? 1 : 0;
    int nz = (eiw[2 * t + 1] != 0) ? 1 : 0;
    atomicAdd(&c_out, outl);
    atomicAdd(&c_nz, nz);
    __syncthreads();
    if (t == 0) { flags[0] = (c_out > 256); flags[1] = (c_nz < 256); }
}

// ---- fused: [0,nbN) convnorm (xb + sign-folded rn); [nbN,nbN+nbH) bucket ----
// ---- hist (LDS, 8192 edges/block); [nbN+nbH, +16) W-fragment prep -----------
__global__ __launch_bounds__(256) void convhist_k(const void* __restrict__ x,
                                                  u32* __restrict__ xb,
                                                  float* __restrict__ rn, int N,
                                                  const int* __restrict__ ei,
                                                  const int* __restrict__ sa,
                                                  int* __restrict__ bcnt, int E,
                                                  const void* __restrict__ W1,
                                                  const void* __restrict__ W2,
                                                  uint4* __restrict__ wf1,
                                                  uint4* __restrict__ wf2,
                                                  const int* __restrict__ flags,
                                                  int nbN, int nbH)
{
    __shared__ int lb[256];
    int b = blockIdx.x;
    if (b < nbN) {
        int i = b * 4 + (threadIdx.x >> 6);
        if (i >= N) return;
        int lane = threadIdx.x & 63;
        u32 u;
        if (flags[0]) {
            const float* q = (const float*)x + (size_t)i * 128 + lane * 2;
            u = pack2(q[0], q[1]);
        } else u = ((const u32*)x)[(size_t)i * 64 + lane];
        xb[(size_t)i * 64 + lane] = u;
        float f0 = bflo(u), f1 = bfhi(u);
        float ss = wsum(f0 * f0 + f1 * f1);
        if (lane == 0) {
            float r = 1.0f / fmaxf(sqrtf(ss), 1e-8f);
            int a = flags[1] ? sa[2 * (size_t)i] : sa[i];
            rn[i] = a ? -r : r;            // sign encodes sensitive attr
        }
    } else if (b < nbN + nbH) {
        int t = threadIdx.x;
        lb[t] = 0;
        __syncthreads();
        int i64 = flags[1];
        size_t base = (size_t)(b - nbN) * 8192;
#pragma unroll 4
        for (int k = 0; k < 32; ++k) {
            size_t e = base + (size_t)k * 256 + t;
            if (e < (size_t)E) {
                int d = ldidx(ei, (size_t)E + e, i64);
                if ((u32)d >= (u32)N) d = 0;
                atomicAdd(&lb[d >> 8], 1);   // bucket = dst>>8 (<256, N<=65536)
            }
        }
        __syncthreads();
        int c = lb[t];
        if (c) atomicAdd(&bcnt[t], c);       // 256 counters: L2/L3-hot
    } else {
        int slot = (b - nbN - nbH) * 256 + threadIdx.x;   // 0..4095
        if (slot >= 4096) return;
        int f32w = flags[0];
        const void* W = (slot < 2048) ? W1 : W2;
        uint4* wf = (slot < 2048) ? wf1 : wf2;
        int s = slot & 2047;
        int lane = s & 63, kk = (s >> 6) & 3, ct = s >> 8;
        int q = lane >> 4, n = lane & 15;
        int col = ct * 16 + n, k0 = kk * 32 + q * 8;
        union { u16 us[8]; uint4 u4; } tmp;
#pragma unroll
        for (int j = 0; j < 8; ++j)
            tmp.us[j] = f2bf(ld1(W, (size_t)(k0 + j) * 128 + col, f32w));
        wf[s] = tmp.u4;
    }
}

// ---- bscan: 1-wave exclusive scan of 256 bucket counts -> bbase, bcur -------
// Also writes bbase[256]=E and rowp[N]=E.
__global__ void bscan_k(const int* __restrict__ bcnt, int* __restrict__ bbase,
                        int* __restrict__ bcur, int* __restrict__ rowp, int N)
{
    int lane = threadIdx.x;   // launched with 64 threads
    int carry = 0;
    for (int base = 0; base < 256; base += 64) {
        int i = base + lane;
        int v = bcnt[i];
        int sc = v;
#pragma unroll
        for (int o = 1; o < 64; o <<= 1) {
            int nv = __shfl_up(sc, o);
            if (lane >= o) sc += nv;
        }
        int excl = carry + sc - v;
        bbase[i] = excl;
        bcur[i] = excl;
        carry += __shfl(sc, 63);
    }
    if (lane == 0) { bbase[256] = carry; rowp[N] = carry; }
}

// ---- bucket: bin edges by dst>>8 into tmp (payload (src<<8)|dst&255) --------
// LDS hist gives per-edge rank; one global atomic per (block,bucket) reserves
// a dense slice -> every bucket's write cursor advances monotonically, write
// frontier = ~NB hot lines, partial pieces merge in L2 (write amp ~1).
__global__ __launch_bounds__(256) void bucket_k(const int* __restrict__ ei,
                                                int* __restrict__ bcur,
                                                u32* __restrict__ tmp,
                                                int E, int N,
                                                const int* __restrict__ flags)
{
    __shared__ int lh[256];
    __shared__ int gb[256];
    int t = threadIdx.x;
    lh[t] = 0;
    __syncthreads();
    int i64 = flags[1];
    size_t base = (size_t)blockIdx.x * 4096;
    u32 pay[16], meta[16];
#pragma unroll
    for (int k = 0; k < 16; ++k) {
        size_t e = base + (size_t)k * 256 + t;
        if (e < (size_t)E) {
            int s = ldidx(ei, e, i64);
            int d = ldidx(ei, (size_t)E + e, i64);
            if ((u32)s >= (u32)N) s = 0;
            if ((u32)d >= (u32)N) d = 0;
            int b = d >> 8;                     // < 256 since N <= 65536
            pay[k] = ((u32)s << 8) | ((u32)d & 0xFFu);
            int r = atomicAdd(&lh[b], 1);
            meta[k] = ((u32)r << 8) | (u32)b;   // rank < 4096 fits
        } else meta[k] = 0xFFFFFFFFu;
    }
    __syncthreads();
    int c = lh[t];
    gb[t] = c ? atomicAdd(&bcur[t], c) : 0;
    __syncthreads();
#pragma unroll
    for (int k = 0; k < 16; ++k) {
        if (meta[k] != 0xFFFFFFFFu) {
            int b = (int)(meta[k] & 0xFFu);
            int r = (int)(meta[k] >> 8);
            tmp[gb[b] + r] = pay[k];
        }
    }
}

// ---- scat2: per-bucket CSR finalize within a 16KB L2-resident window --------
// Block b owns nodes [b<<8,(b+1)<<8); its tmp slice & rec window tile
// [bbase[b], bbase[b+1]). Local LDS hist of 256 node counts + in-block scan
// -> coalesced rowp write; scatter via LDS cursors (no global atomics).
__global__ __launch_bounds__(256) void scat2_k(const int* __restrict__ bbase,
                                               int* __restrict__ rowp,
                                               const u32* __restrict__ tmp,
                                               u32* __restrict__ rec,
                                               int N, int E)
{
    __shared__ int lcnt[256];
    __shared__ int wtot[4];
    int b = blockIdx.x, t = threadIdx.x;
    int lane = t & 63, w = t >> 6;
    int n0 = b << 8;
    int p0 = bbase[b], p1 = bbase[b + 1];
    if (p0 < 0) p0 = 0;
    if (p1 > E) p1 = E;
    lcnt[t] = 0;
    __syncthreads();
    for (int idx = p0 + t; idx < p1; idx += 256)
        atomicAdd(&lcnt[tmp[idx] & 0xFFu], 1);
    __syncthreads();
    int v = lcnt[t];
    int sc = v;
#pragma unroll
    for (int o = 1; o < 64; o <<= 1) {
        int nv = __shfl_up(sc, o);
        if (lane >= o) sc += nv;
    }
    if (lane == 63) wtot[w] = sc;
    __syncthreads();
    int wo = 0;
#pragma unroll
    for (int k = 0; k < 4; ++k) { int s = wtot[k]; if (k < w) wo += s; }
    int excl = wo + sc - v;                 // local exclusive offset
    int node = n0 + t;
    if (node < N) rowp[node] = p0 + excl;   // coalesced CSR rowptr write
    lcnt[t] = excl;                         // reuse as scatter cursor
    __syncthreads();
    for (int idx = p0 + t; idx < p1; idx += 256) {
        u32 pay = tmp[idx];
        int r = atomicAdd(&lcnt[pay & 0xFFu], 1);   // LDS atomic
        int pos = p0 + r;
        if ((u32)pos >= (u32)E) pos = 0;
        rec[pos] = pay >> 8;                        // plain src index
    }
}

// ---- ewcsr: edge weights in CSR order + fused dinv --------------------------
// Wave per dst node; dst row held in regs (read once, sequential); only src
// rows gathered (halves gather volume vs per-edge form). 16 lanes/edge,
// 4 edges/wave in flight, 2x unroll per group for MLP. rec[p] rewritten
// sequentially as (src<<16)|bf16(w). Row weight sum -> dv[i]=rsqrt(1+sum).
// sa folded into sign of rn: prod<0 <=> attrs differ; |prod| = rn_s*rn_d.
__global__ __launch_bounds__(256) void ewcsr_k(const u32* __restrict__ xb,
                                               const float* __restrict__ rn,
                                               const int* __restrict__ rowp,
                                               u32* __restrict__ rec,
                                               float* __restrict__ dv,
                                               int N, int E)
{
    int i = blockIdx.x * 4 + (threadIdx.x >> 6);
    if (i >= N) return;
    int lane = threadIdx.x & 63, g = lane >> 4, j = lane & 15;
    uint4 D = ((const uint4*)(xb + (size_t)i * 64))[j];   // dst row, loop-invariant
    float rni = rn[i];
    int p0 = rowp[i], p1 = rowp[i + 1];
    if (p0 < 0) p0 = 0;
    if (p1 > E) p1 = E;
    float acc = 0.0f;
    int p = p0 + g;
    for (; p + 4 < p1; p += 8) {          // 2 edges per group per iter
        int s0 = (int)rec[p];     if ((u32)s0 >= (u32)N) s0 = 0;
        int s1 = (int)rec[p + 4]; if ((u32)s1 >= (u32)N) s1 = 0;
        uint4 A0 = ((const uint4*)(xb + (size_t)s0 * 64))[j];
        uint4 A1 = ((const uint4*)(xb + (size_t)s1 * 64))[j];
        float d0 = bflo(A0.x) * bflo(D.x) + bfhi(A0.x) * bfhi(D.x)
                 + bflo(A0.y) * bflo(D.y) + bfhi(A0.y) * bfhi(D.y)
                 + bflo(A0.z) * bflo(D.z) + bfhi(A0.z) * bfhi(D.z)
                 + bflo(A0.w) * bflo(D.w) + bfhi(A0.w) * bfhi(D.w);
        float d1 = bflo(A1.x) * bflo(D.x) + bfhi(A1.x) * bfhi(D.x)
                 + bflo(A1.y) * bflo(D.y) + bfhi(A1.y) * bfhi(D.y)
                 + bflo(A1.z) * bflo(D.z) + bfhi(A1.z) * bfhi(D.z)
                 + bflo(A1.w) * bflo(D.w) + bfhi(A1.w) * bfhi(D.w);
#pragma unroll
        for (int o = 8; o > 0; o >>= 1) {
            d0 += __shfl_xor(d0, o);
            d1 += __shfl_xor(d1, o);
        }
        if (j == 0) {
            float pr0 = rn[s0] * rni;
            float w0 = fmaxf(d0 * fabsf(pr0) *
                             ((pr0 < 0.0f) ? 0.36787944117144233f : 1.0f), 1e-4f);
            u16 wb0 = f2bf(w0);
            rec[p] = ((u32)s0 << 16) | wb0;
            acc += bf1(wb0);
            float pr1 = rn[s1] * rni;
            float w1 = fmaxf(d1 * fabsf(pr1) *
                             ((pr1 < 0.0f) ? 0.36787944117144233f : 1.0f), 1e-4f);
            u16 wb1 = f2bf(w1);
            rec[p + 4] = ((u32)s1 << 16) | wb1;
            acc += bf1(wb1);
        }
    }
    if (p < p1) {                          // <=1 leftover edge per group
        int s0 = (int)rec[p]; if ((u32)s0 >= (u32)N) s0 = 0;
        uint4 A0 = ((const uint4*)(xb + (size_t)s0 * 64))[j];
        float d0 = bflo(A0.x) * bflo(D.x) + bfhi(A0.x) * bfhi(D.x)
                 + bflo(A0.y) * bflo(D.y) + bfhi(A0.y) * bfhi(D.y)
                 + bflo(A0.z) * bflo(D.z) + bfhi(A0.z) * bfhi(D.z)
                 + bflo(A0.w) * bflo(D.w) + bfhi(A0.w) * bfhi(D.w);
#pragma unroll
        for (int o = 8; o > 0; o >>= 1) d0 += __shfl_xor(d0, o);
        if (j == 0) {
            float pr0 = rn[s0] * rni;
            float w0 = fmaxf(d0 * fabsf(pr0) *
                             ((pr0 < 0.0f) ? 0.36787944117144233f : 1.0f), 1e-4f);
            u16 wb0 = f2bf(w0);
            rec[p] = ((u32)s0 << 16) | wb0;
            acc += bf1(wb0);
        }
    }
    // combine the 4 group leaders (non-leader lanes hold 0)
    acc += __shfl_xor(acc, 16);
    acc += __shfl_xor(acc, 32);
    if (lane == 0) dv[i] = 1.0f / sqrtf(1.0f + acc);
}

// ---- aggemm: fused Agg + MFMA GEMM, wave-pair per 16-row tile ---------------
// 512 threads = 8 waves = 4 tiles x 2 half-waves. Each pair splits its tile's
// contiguous CSR range at the midpoint; both halves flush reg accumulators
// into the shared Acc[tile] via LDS float atomicAdds (row-change only).
// Phase 2: pair loads same A-fragments from Acc, splits 8 column-tiles 4/4;
// y partials merged via ybuf + barrier. out must NOT alias feat.
__global__ __launch_bounds__(512) void aggemm_k(const u32* __restrict__ feat,
                                                const int* __restrict__ rowp,
                                                const u32* __restrict__ rec,
                                                const float* __restrict__ dinv,
                                                const uint4* __restrict__ wfrag,
                                                const void* __restrict__ bias,
                                                void* __restrict__ out, int outbf,
                                                int N, int E,
                                                const void* __restrict__ Wc,
                                                const void* __restrict__ bc,
                                                float* __restrict__ yout,
                                                const int* __restrict__ flags)
{
    __shared__ float Acc[4][16][132];   // [tile][row][2*lane]; 132: align+banks
    __shared__ float ybuf[4][16];       // odd-half y partials
    int t = threadIdx.x, wave = t >> 6, lane = t & 63;
    int tile = wave >> 1, half = wave & 1;
    int rowbase = blockIdx.x * 64 + tile * 16;

    // row bounds rowp[rowbase..rowbase+16] in lanes 0..16; dinv in lanes 0..15
    int idx = rowbase + lane;
    int rbreg = E;
    if (lane < 17) {
        int ii = idx < N ? idx : N;
        int v = rowp[ii];
        rbreg = v < 0 ? 0 : (v > E ? E : v);
    }
    float dreg = 0.0f;
    if (lane < 16 && idx < N) dreg = dinv[idx];

    // self terms: even half rows 0..7, odd half rows 8..15 (non-atomic init)
    for (int r = half * 8; r < half * 8 + 8; ++r) {
        int i = rowbase + r;
        float s0 = 0.0f, s1 = 0.0f;
        if (i < N) {
            float di = __shfl(dreg, r), sc = di * di;
            u32 u = feat[(size_t)i * 64 + lane];
            s0 = bflo(u) * sc; s1 = bfhi(u) * sc;
        }
        float2 st; st.x = s0; st.y = s1;
        *(float2*)&Acc[tile][r][2 * lane] = st;
    }
    __syncthreads();

    // half-range [lo, hi) of the tile's CSR span
    int P0 = __shfl(rbreg, 0), P16 = __shfl(rbreg, 16);
    int mid = (P0 + P16) >> 1;
    int lo = half ? mid : P0;
    int hi = half ? P16 : mid;
    // cursor init: row containing lo = popcount(bounds <= lo) - 1
    unsigned long long bm = __ballot(lane <= 16 && rbreg <= lo);
    int crow = (int)__popcll(bm) - 1;
    if (crow < 0) crow = 0;
    if (crow > 15) crow = 15;
    int nb = __shfl(rbreg, crow + 1);
    float dic = __shfl(dreg, crow & 15);
    float a0 = 0.0f, a1 = 0.0f;
    int p = lo;
    for (; p + 15 < hi; p += 16) {        // 16 gathers in flight
        u32 rr[16]; int s[16]; u32 v[16]; float dvs[16];
#pragma unroll
        for (int k = 0; k < 16; ++k) {
            rr[k] = rec[p + k];
            s[k] = rr[k] >> 16;
            if (s[k] >= N) s[k] = 0;
        }
#pragma unroll
        for (int k = 0; k < 16; ++k) v[k] = feat[(size_t)s[k] * 64 + lane];
#pragma unroll
        for (int k = 0; k < 16; ++k) dvs[k] = dinv[s[k]];
#pragma unroll
        for (int k = 0; k < 16; ++k) {
            int e = p + k;
            if (e >= nb) {                // row change: flush reg acc (uniform)
                atomicAdd(&Acc[tile][crow][2 * lane], a0);
                atomicAdd(&Acc[tile][crow][2 * lane + 1], a1);
                do { ++crow; nb = __shfl(rbreg, crow + 1); } while (e >= nb);
                dic = __shfl(dreg, crow & 15);
                a0 = 0.0f; a1 = 0.0f;
            }
            float w = bf1((u16)rr[k]) * dic * dvs[k];
            a0 = fmaf(w, bflo(v[k]), a0);
            a1 = fmaf(w, bfhi(v[k]), a1);
        }
    }
    for (; p + 3 < hi; p += 4) {          // 4-deep tail
        u32 rr[4]; int s[4]; u32 v[4]; float dvs[4];
#pragma unroll
        for (int k = 0; k < 4; ++k) {
            rr[k] = rec[p + k];
            s[k] = rr[k] >> 16;
            if (s[k] >= N) s[k] = 0;
        }
#pragma unroll
        for (int k = 0; k < 4; ++k) v[k] = feat[(size_t)s[k] * 64 + lane];
#pragma unroll
        for (int k = 0; k < 4; ++k) dvs[k] = dinv[s[k]];
#pragma unroll
        for (int k = 0; k < 4; ++k) {
            int e = p + k;
            if (e >= nb) {
                atomicAdd(&Acc[tile][crow][2 * lane], a0);
                atomicAdd(&Acc[tile][crow][2 * lane + 1], a1);
                do { ++crow; nb = __shfl(rbreg, crow + 1); } while (e >= nb);
                dic = __shfl(dreg, crow & 15);
                a0 = 0.0f; a1 = 0.0f;
            }
            float w = bf1((u16)rr[k]) * dic * dvs[k];
            a0 = fmaf(w, bflo(v[k]), a0);
            a1 = fmaf(w, bfhi(v[k]), a1);
        }
    }
    for (; p < hi; ++p) {                 // <=3 singles
        u32 r0 = rec[p];
        int s0 = r0 >> 16;
        if (s0 >= N) s0 = 0;
        u32 v0 = feat[(size_t)s0 * 64 + lane];
        float dv0 = dinv[s0];
        if (p >= nb) {
            atomicAdd(&Acc[tile][crow][2 * lane], a0);
            atomicAdd(&Acc[tile][crow][2 * lane + 1], a1);
            do { ++crow; nb = __shfl(rbreg, crow + 1); } while (p >= nb);
            dic = __shfl(dreg, crow & 15);
            a0 = 0.0f; a1 = 0.0f;
        }
        float w = bf1((u16)r0) * dic * dv0;
        a0 = fmaf(w, bflo(v0), a0);
        a1 = fmaf(w, bfhi(v0), a1);
    }
    {   // final flush
        int cr = crow & 15;
        atomicAdd(&Acc[tile][cr][2 * lane], a0);
        atomicAdd(&Acc[tile][cr][2 * lane + 1], a1);
    }
    __syncthreads();

    // ---- phase 2: MFMA gemm; pair splits 8 cts 4/4; A from shared Acc ------
    int q = lane >> 4, n = lane & 15;
    int f32w = flags[0];
    int ct0 = half * 4;
    const float* rowptr = &Acc[tile][n][0];
    short8 a[4];
#pragma unroll
    for (int kk = 0; kk < 4; ++kk) {
        int c0 = kk * 32 + q * 8;
        float2 g0 = *(const float2*)(rowptr + c0);
        float2 g1 = *(const float2*)(rowptr + c0 + 2);
        float2 g2 = *(const float2*)(rowptr + c0 + 4);
        float2 g3 = *(const float2*)(rowptr + c0 + 6);
        uint4 av;
        av.x = pack2(g0.x, g0.y);
        av.y = pack2(g1.x, g1.y);
        av.z = pack2(g2.x, g2.y);
        av.w = pack2(g3.x, g3.y);
        a[kk] = *(short8*)&av;
    }
    floatx4 acc[4];
#pragma unroll
    for (int c = 0; c < 4; ++c) acc[c] = (floatx4){0.f, 0.f, 0.f, 0.f};
#pragma unroll
    for (int c = 0; c < 4; ++c) {
#pragma unroll
        for (int kk = 0; kk < 4; ++kk) {
            uint4 bv = wfrag[((ct0 + c) * 4 + kk) * 64 + lane];
            acc[c] = __builtin_amdgcn_mfma_f32_16x16x32_bf16(
                a[kk], *(short8*)&bv, acc[c], 0, 0, 0);
        }
    }
    float bcv = 0.0f;
    float part[4] = {0.f, 0.f, 0.f, 0.f};
    if (yout) bcv = ld1(bc, 0, f32w);
#pragma unroll
    for (int c = 0; c < 4; ++c) {
        int col = (ct0 + c) * 16 + n;
        float bia = ld1(bias, col, f32w);
        float wcv = yout ? ld1(Wc, col, f32w) : 0.0f;
#pragma unroll
        for (int r = 0; r < 4; ++r) {            // D row = q*4+r, col = n
            int row = rowbase + q * 4 + r;
            float h = fmaxf(acc[c][r] + bia, 0.0f);
            if (row < N) {
                if (outbf) ((u16*)out)[(size_t)row * 128 + col] = f2bf(h);
                else       ((float*)out)[(size_t)row * 128 + col] = h;
            }
            part[r] = fmaf(h, wcv, part[r]);
        }
    }
    float prv[4];
#pragma unroll
    for (int r = 0; r < 4; ++r) {
        float pr = part[r];
#pragma unroll
        for (int o = 8; o > 0; o >>= 1) pr += __shfl_xor(pr, o);   // 16-lane grp
        prv[r] = pr;
    }
    if (yout && half && n == 0) {
#pragma unroll
        for (int r = 0; r < 4; ++r) ybuf[tile][q * 4 + r] = prv[r];
    }
    __syncthreads();
    if (yout && !half && n == 0) {
#pragma unroll
        for (int r = 0; r < 4; ++r) {
            int row = rowbase + q * 4 + r;
            if (row < N) yout[row] = prv[r] + ybuf[tile][q * 4 + r] + bcv;
        }
    }
}

extern "C" void kernel_launch(void* const* d_in, const int* in_sizes, int n_in,
                              void* d_out, int out_size, void* d_ws, size_t ws_size,
                              hipStream_t stream)
{
    const void* x  = d_in[0];
    const int* ei  = (const int*)d_in[1];
    const int* sa  = (const int*)d_in[2];
    const void* W1 = d_in[3];
    const void* b1 = d_in[4];
    const void* W2 = d_in[5];
    const void* b2 = d_in[6];
    const void* Wc = d_in[7];
    const void* bc = d_in[8];
    const int N = in_sizes[2];
    const int E = in_sizes[1] / 2;

    float* y_out = (float*)d_out;
    float* h_out = y_out + N;          // final h (written only by layer 2)
    u32*   h1b   = (u32*)d_in[0];      // layer-1 output (bf16 rows) in x's
                                       // buffer (x dead after convhist)
    u32*   tmp   = (u32*)d_in[0];      // bucket payloads (E*4B <= 3.2 MB);
                                       // consumed by scat2 before aggemm1

    const int nbN = (N + 3) / 4;
    const int nbH = (E + 8191) / 8192;
    const int NB  = (N + 255) / 256;   // dst buckets (<=256 since N<=65536)

    char* p = (char*)d_ws;
    auto carve = [&](size_t bytes) { char* r = p; p += (bytes + 255) & ~(size_t)255; return r; };
    int*   flags = (int*)carve(256);
    float* rn    = (float*)carve((size_t)N * 4);      // sign-folded 1/||x||
    float* dinv  = (float*)carve((size_t)N * 4);
    int*   rowp  = (int*)carve((size_t)(N + 1) * 4);
    int*   bcnt  = (int*)carve(256 * 4);              // bucket histogram
    int*   bbase = (int*)carve(260 * 4);              // bucket bases (+total)
    int*   bcur  = (int*)carve(256 * 4);              // bucket write cursors
    uint4* wf1   = (uint4*)carve(2048 * 16);          // W1 B-fragments, 32 KB
    uint4* wf2   = (uint4*)carve(2048 * 16);          // W2 B-fragments, 32 KB
    u32*   rec   = (u32*)carve((size_t)E * 4);        // (src<<16)|bf16(w)
    u32*   xb    = (u32*)carve((size_t)N * 64 * 4);   // packed-bf16 x (~12.8 MB)

    classify_k<<<1, 1024, 0, stream>>>((const u32*)x, ei, flags, bcnt);
    convhist_k<<<nbN + nbH + 16, 256, 0, stream>>>(x, xb, rn, N, ei, sa, bcnt, E,
                                                   W1, W2, wf1, wf2, flags,
                                                   nbN, nbH);
    bscan_k<<<1, 64, 0, stream>>>(bcnt, bbase, bcur, rowp, N);
    bucket_k<<<(E + 4095) / 4096, 256, 0, stream>>>(ei, bcur, tmp, E, N, flags);
    scat2_k<<<NB, 256, 0, stream>>>(bbase, rowp, tmp, rec, N, E);
    ewcsr_k<<<(N + 3) / 4, 256, 0, stream>>>(xb, rn, rowp, rec, dinv, N, E);

    // layer 1: h1b = relu(Agg(xb)@W1+b1) bf16 -> dead-x buffer (NOT xb: other
    // blocks still gather xb while this writes)
    aggemm_k<<<(N + 63) / 64, 512, 0, stream>>>(xb, rowp, rec, dinv, wf1, b1,
                                                h1b, 1, N, E,
                                                nullptr, nullptr, nullptr, flags);
    // layer 2: h = relu(Agg(h1b)@W2+b2) f32 -> d_out, + y
    aggemm_k<<<(N + 63) / 64, 512, 0, stream>>>(h1b, rowp, rec, dinv, wf2, b2,
                                                h_out, 0, N, E,
                                                Wc, bc, y_out, flags);
}

// Round 7
// 282.486 us; speedup vs baseline: 1.1384x; 1.1384x over previous
//
#include <hip/hip_runtime.h>

// FnRGNN: 2-layer GCN w/ cosine-sim edge weights. f32 math, f32 output
// [y(N), h(N*128)]. Inputs runtime-classified (f32/bf16, i64/i32).
// R19: REVERT to R15 split structure (276us proven; R17/R18 fused aggemm
// variants both lost: 64-row MFMA tile forces 782-block grid -> gather phase
// latency-starved at ~25-28% occupancy; Tb round-trip saving ~8us < fusion
// penalty ~30-40us). One change vs R15: ewcsr main loop deepened to 4 edges
// per 16-lane group (16 rows in flight/wave, was 8) -- same math, +12 VGPR.
// Bucket-level hist (R15), two-level bucket scatter (R14), ewcsr CSR-order
// weights w/ fused dinv (R13). MFMA gemm w/ prepacked B-fragments
// (identity-proven layouts). CSR rec = (src<<16)|bf16(w) packed 4B
// (N<=65536). Agg-first GCN form. ws ~= 16.9 MB.

typedef unsigned short u16;
typedef unsigned int u32;
typedef __attribute__((ext_vector_type(8))) short short8;
typedef __attribute__((ext_vector_type(4))) float floatx4;

__device__ __forceinline__ float bflo(u32 u){ return __uint_as_float(u << 16); }
__device__ __forceinline__ float bfhi(u32 u){ return __uint_as_float(u & 0xFFFF0000u); }
__device__ __forceinline__ float bf1(u16 u){ return __uint_as_float(((u32)u) << 16); }
__device__ __forceinline__ u16 f2bf(float f){
    u32 u = __float_as_uint(f);
    u += 0x7FFFu + ((u >> 16) & 1u);   // RNE
    return (u16)(u >> 16);
}
__device__ __forceinline__ u32 pack2(float a, float b){
    return (u32)f2bf(a) | ((u32)f2bf(b) << 16);
}
__device__ __forceinline__ float wsum(float v){
#pragma unroll
    for (int o = 32; o > 0; o >>= 1) v += __shfl_xor(v, o, 64);
    return v;
}
__device__ __forceinline__ float ld1(const void* p, size_t idx, int f32){
    return f32 ? ((const float*)p)[idx] : bf1(((const u16*)p)[idx]);
}
__device__ __forceinline__ int ldidx(const int* p, size_t i, int i64){
    return i64 ? p[2 * i] : p[i];   // int64 low word
}

// ---- classify: flags[0]=reals are f32, flags[1]=ints are i64; zero bcnt -----
__global__ void classify_k(const u32* __restrict__ xw, const int* __restrict__ eiw,
                           int* __restrict__ flags, int* __restrict__ bcnt)
{
    __shared__ int c_out, c_nz;
    int t = threadIdx.x;
    if (t == 0) { c_out = 0; c_nz = 0; }
    if (t < 256) bcnt[t] = 0;
    __syncthreads();
    u32 w = xw[t];
    int e = (w >> 7) & 0xFF;
    int outl = (e < 110 || e > 140) ? 1 : 0;
    int nz = (eiw[2 * t + 1] != 0) ? 1 : 0;
    atomicAdd(&c_out, outl);
    atomicAdd(&c_nz, nz);
    __syncthreads();
    if (t == 0) { flags[0] = (c_out > 256); flags[1] = (c_nz < 256); }
}

// ---- fused: [0,nbN) convnorm (xb + sign-folded rn); [nbN,nbN+nbH) bucket ----
// ---- hist (LDS, 8192 edges/block); [nbN+nbH, +16) W-fragment prep -----------
__global__ __launch_bounds__(256) void convhist_k(const void* __restrict__ x,
                                                  u32* __restrict__ xb,
                                                  float* __restrict__ rn, int N,
                                                  const int* __restrict__ ei,
                                                  const int* __restrict__ sa,
                                                  int* __restrict__ bcnt, int E,
                                                  const void* __restrict__ W1,
                                                  const void* __restrict__ W2,
                                                  uint4* __restrict__ wf1,
                                                  uint4* __restrict__ wf2,
                                                  const int* __restrict__ flags,
                                                  int nbN, int nbH)
{
    __shared__ int lb[256];
    int b = blockIdx.x;
    if (b < nbN) {
        int i = b * 4 + (threadIdx.x >> 6);
        if (i >= N) return;
        int lane = threadIdx.x & 63;
        u32 u;
        if (flags[0]) {
            const float* q = (const float*)x + (size_t)i * 128 + lane * 2;
            u = pack2(q[0], q[1]);
        } else u = ((const u32*)x)[(size_t)i * 64 + lane];
        xb[(size_t)i * 64 + lane] = u;
        float f0 = bflo(u), f1 = bfhi(u);
        float ss = wsum(f0 * f0 + f1 * f1);
        if (lane == 0) {
            float r = 1.0f / fmaxf(sqrtf(ss), 1e-8f);
            int a = flags[1] ? sa[2 * (size_t)i] : sa[i];
            rn[i] = a ? -r : r;            // sign encodes sensitive attr
        }
    } else if (b < nbN + nbH) {
        int t = threadIdx.x;
        lb[t] = 0;
        __syncthreads();
        int i64 = flags[1];
        size_t base = (size_t)(b - nbN) * 8192;
#pragma unroll 4
        for (int k = 0; k < 32; ++k) {
            size_t e = base + (size_t)k * 256 + t;
            if (e < (size_t)E) {
                int d = ldidx(ei, (size_t)E + e, i64);
                if ((u32)d >= (u32)N) d = 0;
                atomicAdd(&lb[d >> 8], 1);   // bucket = dst>>8 (<256, N<=65536)
            }
        }
        __syncthreads();
        int c = lb[t];
        if (c) atomicAdd(&bcnt[t], c);       // 256 counters: L2/L3-hot
    } else {
        int slot = (b - nbN - nbH) * 256 + threadIdx.x;   // 0..4095
        if (slot >= 4096) return;
        int f32w = flags[0];
        const void* W = (slot < 2048) ? W1 : W2;
        uint4* wf = (slot < 2048) ? wf1 : wf2;
        int s = slot & 2047;
        int lane = s & 63, kk = (s >> 6) & 3, ct = s >> 8;
        int q = lane >> 4, n = lane & 15;
        int col = ct * 16 + n, k0 = kk * 32 + q * 8;
        union { u16 us[8]; uint4 u4; } tmp;
#pragma unroll
        for (int j = 0; j < 8; ++j)
            tmp.us[j] = f2bf(ld1(W, (size_t)(k0 + j) * 128 + col, f32w));
        wf[s] = tmp.u4;
    }
}

// ---- bscan: 1-wave exclusive scan of 256 bucket counts -> bbase, bcur -------
// Also writes bbase[256]=E and rowp[N]=E.
__global__ void bscan_k(const int* __restrict__ bcnt, int* __restrict__ bbase,
                        int* __restrict__ bcur, int* __restrict__ rowp, int N)
{
    int lane = threadIdx.x;   // launched with 64 threads
    int carry = 0;
    for (int base = 0; base < 256; base += 64) {
        int i = base + lane;
        int v = bcnt[i];
        int sc = v;
#pragma unroll
        for (int o = 1; o < 64; o <<= 1) {
            int nv = __shfl_up(sc, o);
            if (lane >= o) sc += nv;
        }
        int excl = carry + sc - v;
        bbase[i] = excl;
        bcur[i] = excl;
        carry += __shfl(sc, 63);
    }
    if (lane == 0) { bbase[256] = carry; rowp[N] = carry; }
}

// ---- bucket: bin edges by dst>>8 into tmp (payload (src<<8)|dst&255) --------
// LDS hist gives per-edge rank; one global atomic per (block,bucket) reserves
// a dense slice -> every bucket's write cursor advances monotonically, write
// frontier = ~NB hot lines, partial pieces merge in L2 (write amp ~1).
__global__ __launch_bounds__(256) void bucket_k(const int* __restrict__ ei,
                                                int* __restrict__ bcur,
                                                u32* __restrict__ tmp,
                                                int E, int N,
                                                const int* __restrict__ flags)
{
    __shared__ int lh[256];
    __shared__ int gb[256];
    int t = threadIdx.x;
    lh[t] = 0;
    __syncthreads();
    int i64 = flags[1];
    size_t base = (size_t)blockIdx.x * 4096;
    u32 pay[16], meta[16];
#pragma unroll
    for (int k = 0; k < 16; ++k) {
        size_t e = base + (size_t)k * 256 + t;
        if (e < (size_t)E) {
            int s = ldidx(ei, e, i64);
            int d = ldidx(ei, (size_t)E + e, i64);
            if ((u32)s >= (u32)N) s = 0;
            if ((u32)d >= (u32)N) d = 0;
            int b = d >> 8;                     // < 256 since N <= 65536
            pay[k] = ((u32)s << 8) | ((u32)d & 0xFFu);
            int r = atomicAdd(&lh[b], 1);
            meta[k] = ((u32)r << 8) | (u32)b;   // rank < 4096 fits
        } else meta[k] = 0xFFFFFFFFu;
    }
    __syncthreads();
    int c = lh[t];
    gb[t] = c ? atomicAdd(&bcur[t], c) : 0;
    __syncthreads();
#pragma unroll
    for (int k = 0; k < 16; ++k) {
        if (meta[k] != 0xFFFFFFFFu) {
            int b = (int)(meta[k] & 0xFFu);
            int r = (int)(meta[k] >> 8);
            tmp[gb[b] + r] = pay[k];
        }
    }
}

// ---- scat2: per-bucket CSR finalize within a 16KB L2-resident window --------
// Block b owns nodes [b<<8,(b+1)<<8); its tmp slice & rec window tile
// [bbase[b], bbase[b+1]). Local LDS hist of 256 node counts + in-block scan
// -> coalesced rowp write; scatter via LDS cursors (no global atomics).
__global__ __launch_bounds__(256) void scat2_k(const int* __restrict__ bbase,
                                               int* __restrict__ rowp,
                                               const u32* __restrict__ tmp,
                                               u32* __restrict__ rec,
                                               int N, int E)
{
    __shared__ int lcnt[256];
    __shared__ int wtot[4];
    int b = blockIdx.x, t = threadIdx.x;
    int lane = t & 63, w = t >> 6;
    int n0 = b << 8;
    int p0 = bbase[b], p1 = bbase[b + 1];
    if (p0 < 0) p0 = 0;
    if (p1 > E) p1 = E;
    lcnt[t] = 0;
    __syncthreads();
    for (int idx = p0 + t; idx < p1; idx += 256)
        atomicAdd(&lcnt[tmp[idx] & 0xFFu], 1);
    __syncthreads();
    int v = lcnt[t];
    int sc = v;
#pragma unroll
    for (int o = 1; o < 64; o <<= 1) {
        int nv = __shfl_up(sc, o);
        if (lane >= o) sc += nv;
    }
    if (lane == 63) wtot[w] = sc;
    __syncthreads();
    int wo = 0;
#pragma unroll
    for (int k = 0; k < 4; ++k) { int s = wtot[k]; if (k < w) wo += s; }
    int excl = wo + sc - v;                 // local exclusive offset
    int node = n0 + t;
    if (node < N) rowp[node] = p0 + excl;   // coalesced CSR rowptr write
    lcnt[t] = excl;                         // reuse as scatter cursor
    __syncthreads();
    for (int idx = p0 + t; idx < p1; idx += 256) {
        u32 pay = tmp[idx];
        int r = atomicAdd(&lcnt[pay & 0xFFu], 1);   // LDS atomic
        int pos = p0 + r;
        if ((u32)pos >= (u32)E) pos = 0;
        rec[pos] = pay >> 8;                        // plain src index
    }
}

// ---- ewcsr: edge weights in CSR order + fused dinv --------------------------
// Wave per dst node; dst row held in regs (read once, sequential); only src
// rows gathered (halves gather volume vs per-edge form). 16 lanes/edge,
// 4 edges/wave, 4x unroll per group (16 rows in flight/wave) for MLP.
// rec[p] rewritten sequentially as (src<<16)|bf16(w). Row weight sum ->
// dv[i]=rsqrt(1+sum). sa folded into sign of rn: prod<0 <=> attrs differ;
// |prod| = rn_s*rn_d.
__global__ __launch_bounds__(256) void ewcsr_k(const u32* __restrict__ xb,
                                               const float* __restrict__ rn,
                                               const int* __restrict__ rowp,
                                               u32* __restrict__ rec,
                                               float* __restrict__ dv,
                                               int N, int E)
{
    int i = blockIdx.x * 4 + (threadIdx.x >> 6);
    if (i >= N) return;
    int lane = threadIdx.x & 63, g = lane >> 4, j = lane & 15;
    uint4 D = ((const uint4*)(xb + (size_t)i * 64))[j];   // dst row, loop-invariant
    float rni = rn[i];
    int p0 = rowp[i], p1 = rowp[i + 1];
    if (p0 < 0) p0 = 0;
    if (p1 > E) p1 = E;
    float acc = 0.0f;
    int p = p0 + g;
    for (; p + 12 < p1; p += 16) {        // 4 edges per group per iter
        int s0 = (int)rec[p];      if ((u32)s0 >= (u32)N) s0 = 0;
        int s1 = (int)rec[p + 4];  if ((u32)s1 >= (u32)N) s1 = 0;
        int s2 = (int)rec[p + 8];  if ((u32)s2 >= (u32)N) s2 = 0;
        int s3 = (int)rec[p + 12]; if ((u32)s3 >= (u32)N) s3 = 0;
        uint4 A0 = ((const uint4*)(xb + (size_t)s0 * 64))[j];
        uint4 A1 = ((const uint4*)(xb + (size_t)s1 * 64))[j];
        uint4 A2 = ((const uint4*)(xb + (size_t)s2 * 64))[j];
        uint4 A3 = ((const uint4*)(xb + (size_t)s3 * 64))[j];
        float d0 = bflo(A0.x) * bflo(D.x) + bfhi(A0.x) * bfhi(D.x)
                 + bflo(A0.y) * bflo(D.y) + bfhi(A0.y) * bfhi(D.y)
                 + bflo(A0.z) * bflo(D.z) + bfhi(A0.z) * bfhi(D.z)
                 + bflo(A0.w) * bflo(D.w) + bfhi(A0.w) * bfhi(D.w);
        float d1 = bflo(A1.x) * bflo(D.x) + bfhi(A1.x) * bfhi(D.x)
                 + bflo(A1.y) * bflo(D.y) + bfhi(A1.y) * bfhi(D.y)
                 + bflo(A1.z) * bflo(D.z) + bfhi(A1.z) * bfhi(D.z)
                 + bflo(A1.w) * bflo(D.w) + bfhi(A1.w) * bfhi(D.w);
        float d2 = bflo(A2.x) * bflo(D.x) + bfhi(A2.x) * bfhi(D.x)
                 + bflo(A2.y) * bflo(D.y) + bfhi(A2.y) * bfhi(D.y)
                 + bflo(A2.z) * bflo(D.z) + bfhi(A2.z) * bfhi(D.z)
                 + bflo(A2.w) * bflo(D.w) + bfhi(A2.w) * bfhi(D.w);
        float d3 = bflo(A3.x) * bflo(D.x) + bfhi(A3.x) * bfhi(D.x)
                 + bflo(A3.y) * bflo(D.y) + bfhi(A3.y) * bfhi(D.y)
                 + bflo(A3.z) * bflo(D.z) + bfhi(A3.z) * bfhi(D.z)
                 + bflo(A3.w) * bflo(D.w) + bfhi(A3.w) * bfhi(D.w);
#pragma unroll
        for (int o = 8; o > 0; o >>= 1) {
            d0 += __shfl_xor(d0, o);
            d1 += __shfl_xor(d1, o);
            d2 += __shfl_xor(d2, o);
            d3 += __shfl_xor(d3, o);
        }
        if (j == 0) {
            float pr0 = rn[s0] * rni;
            float w0 = fmaxf(d0 * fabsf(pr0) *
                             ((pr0 < 0.0f) ? 0.36787944117144233f : 1.0f), 1e-4f);
            u16 wb0 = f2bf(w0);
            rec[p] = ((u32)s0 << 16) | wb0;
            acc += bf1(wb0);
            float pr1 = rn[s1] * rni;
            float w1 = fmaxf(d1 * fabsf(pr1) *
                             ((pr1 < 0.0f) ? 0.36787944117144233f : 1.0f), 1e-4f);
            u16 wb1 = f2bf(w1);
            rec[p + 4] = ((u32)s1 << 16) | wb1;
            acc += bf1(wb1);
            float pr2 = rn[s2] * rni;
            float w2 = fmaxf(d2 * fabsf(pr2) *
                             ((pr2 < 0.0f) ? 0.36787944117144233f : 1.0f), 1e-4f);
            u16 wb2 = f2bf(w2);
            rec[p + 8] = ((u32)s2 << 16) | wb2;
            acc += bf1(wb2);
            float pr3 = rn[s3] * rni;
            float w3 = fmaxf(d3 * fabsf(pr3) *
                             ((pr3 < 0.0f) ? 0.36787944117144233f : 1.0f), 1e-4f);
            u16 wb3 = f2bf(w3);
            rec[p + 12] = ((u32)s3 << 16) | wb3;
            acc += bf1(wb3);
        }
    }
    for (; p + 4 < p1; p += 8) {          // 2-edge tail
        int s0 = (int)rec[p];     if ((u32)s0 >= (u32)N) s0 = 0;
        int s1 = (int)rec[p + 4]; if ((u32)s1 >= (u32)N) s1 = 0;
        uint4 A0 = ((const uint4*)(xb + (size_t)s0 * 64))[j];
        uint4 A1 = ((const uint4*)(xb + (size_t)s1 * 64))[j];
        float d0 = bflo(A0.x) * bflo(D.x) + bfhi(A0.x) * bfhi(D.x)
                 + bflo(A0.y) * bflo(D.y) + bfhi(A0.y) * bfhi(D.y)
                 + bflo(A0.z) * bflo(D.z) + bfhi(A0.z) * bfhi(D.z)
                 + bflo(A0.w) * bflo(D.w) + bfhi(A0.w) * bfhi(D.w);
        float d1 = bflo(A1.x) * bflo(D.x) + bfhi(A1.x) * bfhi(D.x)
                 + bflo(A1.y) * bflo(D.y) + bfhi(A1.y) * bfhi(D.y)
                 + bflo(A1.z) * bflo(D.z) + bfhi(A1.z) * bfhi(D.z)
                 + bflo(A1.w) * bflo(D.w) + bfhi(A1.w) * bfhi(D.w);
#pragma unroll
        for (int o = 8; o > 0; o >>= 1) {
            d0 += __shfl_xor(d0, o);
            d1 += __shfl_xor(d1, o);
        }
        if (j == 0) {
            float pr0 = rn[s0] * rni;
            float w0 = fmaxf(d0 * fabsf(pr0) *
                             ((pr0 < 0.0f) ? 0.36787944117144233f : 1.0f), 1e-4f);
            u16 wb0 = f2bf(w0);
            rec[p] = ((u32)s0 << 16) | wb0;
            acc += bf1(wb0);
            float pr1 = rn[s1] * rni;
            float w1 = fmaxf(d1 * fabsf(pr1) *
                             ((pr1 < 0.0f) ? 0.36787944117144233f : 1.0f), 1e-4f);
            u16 wb1 = f2bf(w1);
            rec[p + 4] = ((u32)s1 << 16) | wb1;
            acc += bf1(wb1);
        }
    }
    if (p < p1) {                          // <=1 leftover edge per group
        int s0 = (int)rec[p]; if ((u32)s0 >= (u32)N) s0 = 0;
        uint4 A0 = ((const uint4*)(xb + (size_t)s0 * 64))[j];
        float d0 = bflo(A0.x) * bflo(D.x) + bfhi(A0.x) * bfhi(D.x)
                 + bflo(A0.y) * bflo(D.y) + bfhi(A0.y) * bfhi(D.y)
                 + bflo(A0.z) * bflo(D.z) + bfhi(A0.z) * bfhi(D.z)
                 + bflo(A0.w) * bflo(D.w) + bfhi(A0.w) * bfhi(D.w);
#pragma unroll
        for (int o = 8; o > 0; o >>= 1) d0 += __shfl_xor(d0, o);
        if (j == 0) {
            float pr0 = rn[s0] * rni;
            float w0 = fmaxf(d0 * fabsf(pr0) *
                             ((pr0 < 0.0f) ? 0.36787944117144233f : 1.0f), 1e-4f);
            u16 wb0 = f2bf(w0);
            rec[p] = ((u32)s0 << 16) | wb0;
            acc += bf1(wb0);
        }
    }
    // combine the 4 group leaders (non-leader lanes hold 0)
    acc += __shfl_xor(acc, 16);
    acc += __shfl_xor(acc, 32);
    if (lane == 0) dv[i] = 1.0f / sqrtf(1.0f + acc);
}

// ---- agg: Tb[i](bf16) = dinv_i^2*feat[i] + sum_p w_p*dinv_i*dinv_s*feat[s] --
// feat packed-bf16 rows; wave/node; rec = (src<<16)|bf16(w); unroll-8 ILP.
__global__ __launch_bounds__(256) void agg_k(const u32* __restrict__ feat,
                                             const int* __restrict__ rowp,
                                             const u32* __restrict__ rec,
                                             const float* __restrict__ dinv,
                                             u32* __restrict__ Tb, int N, int E)
{
    int i = blockIdx.x * 4 + (threadIdx.x >> 6);
    if (i >= N) return;
    int lane = threadIdx.x & 63;
    float di = dinv[i], sc = di * di;
    u32 u = feat[(size_t)i * 64 + lane];
    float a0 = bflo(u) * sc, a1 = bfhi(u) * sc;
    int p0 = rowp[i], p1 = rowp[i + 1];
    if (p0 < 0) p0 = 0;
    if (p1 > E) p1 = E;
    int p = p0;
    for (; p + 7 < p1; p += 8) {
        u32 r[8]; int s[8]; u32 v[8];
#pragma unroll
        for (int k = 0; k < 8; ++k) {
            r[k] = rec[p + k];
            s[k] = r[k] >> 16;
            if (s[k] >= N) s[k] = 0;
        }
#pragma unroll
        for (int k = 0; k < 8; ++k) v[k] = feat[(size_t)s[k] * 64 + lane];
#pragma unroll
        for (int k = 0; k < 8; ++k) {
            float w = bf1((u16)r[k]) * di * dinv[s[k]];
            a0 = fmaf(w, bflo(v[k]), a0);
            a1 = fmaf(w, bfhi(v[k]), a1);
        }
    }
    for (; p + 1 < p1; p += 2) {
        u32 r0 = rec[p], r1 = rec[p + 1];
        int s0 = r0 >> 16, s1 = r1 >> 16;
        if (s0 >= N) s0 = 0;
        if (s1 >= N) s1 = 0;
        u32 v0 = feat[(size_t)s0 * 64 + lane];
        u32 v1 = feat[(size_t)s1 * 64 + lane];
        float w0 = bf1((u16)r0) * di * dinv[s0];
        float w1 = bf1((u16)r1) * di * dinv[s1];
        a0 = fmaf(w0, bflo(v0), a0); a1 = fmaf(w0, bfhi(v0), a1);
        a0 = fmaf(w1, bflo(v1), a0); a1 = fmaf(w1, bfhi(v1), a1);
    }
    if (p < p1) {
        u32 r0 = rec[p];
        int s0 = r0 >> 16;
        if (s0 >= N) s0 = 0;
        u32 v0 = feat[(size_t)s0 * 64 + lane];
        float w0 = bf1((u16)r0) * di * dinv[s0];
        a0 = fmaf(w0, bflo(v0), a0); a1 = fmaf(w0, bfhi(v0), a1);
    }
    Tb[(size_t)i * 64 + lane] = pack2(a0, a1);
}

// ---- MFMA GEMM: out = relu(Tb@W + bias); 64 rows/block, wave = 16 rows ------
// A direct from global (4 uint4/lane); B from pre-packed wfrag (L2, coalesced).
// No LDS, no barriers. Layouts identity-proven (R4 vs R5 bit-identity).
__global__ __launch_bounds__(256) void gemm_m(const u32* __restrict__ Tb,
                                              const uint4* __restrict__ wfrag,
                                              const void* __restrict__ bias,
                                              void* __restrict__ out, int outbf,
                                              int N,
                                              const void* __restrict__ Wc,
                                              const void* __restrict__ bc,
                                              float* __restrict__ yout,
                                              const int* __restrict__ flags)
{
    int t = threadIdx.x, wave = t >> 6, lane = t & 63;
    int q = lane >> 4, n = lane & 15;
    int f32w = flags[0];
    int rowbase = blockIdx.x * 64 + wave * 16;
    int arow = rowbase + n; if (arow > N - 1) arow = N - 1;
    const uint4* ap = (const uint4*)(Tb + (size_t)arow * 64);
    short8 a[4];
#pragma unroll
    for (int kk = 0; kk < 4; ++kk) {
        uint4 av = ap[kk * 4 + q];          // row arow, k = kk*32 + q*8 .. +7
        a[kk] = *(short8*)&av;
    }
    floatx4 acc[8];
#pragma unroll
    for (int ct = 0; ct < 8; ++ct) acc[ct] = (floatx4){0.f, 0.f, 0.f, 0.f};
#pragma unroll
    for (int ct = 0; ct < 8; ++ct) {
#pragma unroll
        for (int kk = 0; kk < 4; ++kk) {
            uint4 bv = wfrag[(ct * 4 + kk) * 64 + lane];
            acc[ct] = __builtin_amdgcn_mfma_f32_16x16x32_bf16(
                a[kk], *(short8*)&bv, acc[ct], 0, 0, 0);
        }
    }
    float bcv = 0.0f;
    float part[4] = {0.f, 0.f, 0.f, 0.f};
    if (yout) bcv = ld1(bc, 0, f32w);
#pragma unroll
    for (int ct = 0; ct < 8; ++ct) {
        int col = ct * 16 + n;
        float bia = ld1(bias, col, f32w);
        float wcv = yout ? ld1(Wc, col, f32w) : 0.0f;
#pragma unroll
        for (int r = 0; r < 4; ++r) {            // D row = q*4+r, col = n
            int row = rowbase + q * 4 + r;
            float h = fmaxf(acc[ct][r] + bia, 0.0f);
            if (row < N) {
                if (outbf) ((u16*)out)[(size_t)row * 128 + col] = f2bf(h);
                else       ((float*)out)[(size_t)row * 128 + col] = h;
            }
            part[r] = fmaf(h, wcv, part[r]);
        }
    }
    if (yout) {
#pragma unroll
        for (int r = 0; r < 4; ++r) {
            float pr = part[r];
#pragma unroll
            for (int o = 8; o > 0; o >>= 1) pr += __shfl_xor(pr, o); // 16-lane grp
            int row = rowbase + q * 4 + r;
            if (n == 0 && row < N) yout[row] = pr + bcv;
        }
    }
}

extern "C" void kernel_launch(void* const* d_in, const int* in_sizes, int n_in,
                              void* d_out, int out_size, void* d_ws, size_t ws_size,
                              hipStream_t stream)
{
    const void* x  = d_in[0];
    const int* ei  = (const int*)d_in[1];
    const int* sa  = (const int*)d_in[2];
    const void* W1 = d_in[3];
    const void* b1 = d_in[4];
    const void* W2 = d_in[5];
    const void* b2 = d_in[6];
    const void* Wc = d_in[7];
    const void* bc = d_in[8];
    const int N = in_sizes[2];
    const int E = in_sizes[1] / 2;

    float* y_out = (float*)d_out;
    float* h_out = y_out + N;          // final h (written only by gemm2)
    u32*   Tbuf  = (u32*)d_in[0];      // T1b then T2b in x's buffer (x dead
                                       // after convhist; >= 12.8 MB)
    u32*   tmp   = (u32*)d_in[0];      // bucket payloads (E*4B <= 3.2 MB);
                                       // consumed by scat2 before agg reuses buf

    const int nbN = (N + 3) / 4;
    const int nbH = (E + 8191) / 8192;
    const int NB  = (N + 255) / 256;   // dst buckets (<=256 since N<=65536)

    char* p = (char*)d_ws;
    auto carve = [&](size_t bytes) { char* r = p; p += (bytes + 255) & ~(size_t)255; return r; };
    int*   flags = (int*)carve(256);
    float* rn    = (float*)carve((size_t)N * 4);      // sign-folded 1/||x||
    float* dinv  = (float*)carve((size_t)N * 4);
    int*   rowp  = (int*)carve((size_t)(N + 1) * 4);
    int*   bcnt  = (int*)carve(256 * 4);              // bucket histogram
    int*   bbase = (int*)carve(260 * 4);              // bucket bases (+total)
    int*   bcur  = (int*)carve(256 * 4);              // bucket write cursors
    uint4* wf1   = (uint4*)carve(2048 * 16);          // W1 B-fragments, 32 KB
    uint4* wf2   = (uint4*)carve(2048 * 16);          // W2 B-fragments, 32 KB
    u32*   rec   = (u32*)carve((size_t)E * 4);        // (src<<16)|bf16(w)
    u32*   xb    = (u32*)carve((size_t)N * 64 * 4);   // xb, then h1b (~16.9 MB)

    classify_k<<<1, 1024, 0, stream>>>((const u32*)x, ei, flags, bcnt);
    convhist_k<<<nbN + nbH + 16, 256, 0, stream>>>(x, xb, rn, N, ei, sa, bcnt, E,
                                                   W1, W2, wf1, wf2, flags,
                                                   nbN, nbH);
    bscan_k<<<1, 64, 0, stream>>>(bcnt, bbase, bcur, rowp, N);
    bucket_k<<<(E + 4095) / 4096, 256, 0, stream>>>(ei, bcur, tmp, E, N, flags);
    scat2_k<<<NB, 256, 0, stream>>>(bbase, rowp, tmp, rec, N, E);
    ewcsr_k<<<(N + 3) / 4, 256, 0, stream>>>(xb, rn, rowp, rec, dinv, N, E);

    // layer 1: T1b = Agg(xb) -> x buf; h1b = relu(T1b@W1+b1) bf16 -> ws (xb dead)
    agg_k<<<(N + 3) / 4, 256, 0, stream>>>(xb, rowp, rec, dinv, Tbuf, N, E);
    gemm_m<<<(N + 63) / 64, 256, 0, stream>>>(Tbuf, wf1, b1, xb, 1, N,
                                              nullptr, nullptr, nullptr, flags);
    // layer 2: T2b = Agg(h1b) -> x buf; h = relu(T2b@W2+b2) f32 -> d_out + y
    agg_k<<<(N + 3) / 4, 256, 0, stream>>>(xb, rowp, rec, dinv, Tbuf, N, E);
    gemm_m<<<(N + 63) / 64, 256, 0, stream>>>(Tbuf, wf2, b2, h_out, 0, N,
                                              Wc, bc, y_out, flags);
}

// Round 8
// 276.303 us; speedup vs baseline: 1.1639x; 1.0224x over previous
//
#include <hip/hip_runtime.h>

// FnRGNN: 2-layer GCN w/ cosine-sim edge weights. f32 math, f32 output
// [y(N), h(N*128)]. Inputs runtime-classified (f32/bf16, i64/i32).
// R20: R15 structure (276us proven). ewcsr: R19's 4-deep REVERTED (regressed
// +6us: serial 4-weight j==0 epilogue + deg>=13 main-loop requirement, not
// depth-limited) back to proven 2-deep; weight epilogue now split across
// lanes j=0/j=1 (both have d0,d1 post-reduction; each computes+writes one
// edge) -> serial section halved; row-sum reduce gains one shfl_xor(1)
// stage (per row, not per edge). Bucket-level hist (R15), two-level bucket
// scatter (R14), ewcsr CSR-order weights w/ fused dinv (R13). MFMA gemm w/
// prepacked B-fragments (identity-proven layouts). CSR rec = (src<<16)|
// bf16(w) packed 4B (N<=65536). Agg-first GCN form. ws ~= 16.9 MB.

typedef unsigned short u16;
typedef unsigned int u32;
typedef __attribute__((ext_vector_type(8))) short short8;
typedef __attribute__((ext_vector_type(4))) float floatx4;

__device__ __forceinline__ float bflo(u32 u){ return __uint_as_float(u << 16); }
__device__ __forceinline__ float bfhi(u32 u){ return __uint_as_float(u & 0xFFFF0000u); }
__device__ __forceinline__ float bf1(u16 u){ return __uint_as_float(((u32)u) << 16); }
__device__ __forceinline__ u16 f2bf(float f){
    u32 u = __float_as_uint(f);
    u += 0x7FFFu + ((u >> 16) & 1u);   // RNE
    return (u16)(u >> 16);
}
__device__ __forceinline__ u32 pack2(float a, float b){
    return (u32)f2bf(a) | ((u32)f2bf(b) << 16);
}
__device__ __forceinline__ float wsum(float v){
#pragma unroll
    for (int o = 32; o > 0; o >>= 1) v += __shfl_xor(v, o, 64);
    return v;
}
__device__ __forceinline__ float ld1(const void* p, size_t idx, int f32){
    return f32 ? ((const float*)p)[idx] : bf1(((const u16*)p)[idx]);
}
__device__ __forceinline__ int ldidx(const int* p, size_t i, int i64){
    return i64 ? p[2 * i] : p[i];   // int64 low word
}

// ---- classify: flags[0]=reals are f32, flags[1]=ints are i64; zero bcnt -----
__global__ void classify_k(const u32* __restrict__ xw, const int* __restrict__ eiw,
                           int* __restrict__ flags, int* __restrict__ bcnt)
{
    __shared__ int c_out, c_nz;
    int t = threadIdx.x;
    if (t == 0) { c_out = 0; c_nz = 0; }
    if (t < 256) bcnt[t] = 0;
    __syncthreads();
    u32 w = xw[t];
    int e = (w >> 7) & 0xFF;
    int outl = (e < 110 || e > 140) ? 1 : 0;
    int nz = (eiw[2 * t + 1] != 0) ? 1 : 0;
    atomicAdd(&c_out, outl);
    atomicAdd(&c_nz, nz);
    __syncthreads();
    if (t == 0) { flags[0] = (c_out > 256); flags[1] = (c_nz < 256); }
}

// ---- fused: [0,nbN) convnorm (xb + sign-folded rn); [nbN,nbN+nbH) bucket ----
// ---- hist (LDS, 8192 edges/block); [nbN+nbH, +16) W-fragment prep -----------
__global__ __launch_bounds__(256) void convhist_k(const void* __restrict__ x,
                                                  u32* __restrict__ xb,
                                                  float* __restrict__ rn, int N,
                                                  const int* __restrict__ ei,
                                                  const int* __restrict__ sa,
                                                  int* __restrict__ bcnt, int E,
                                                  const void* __restrict__ W1,
                                                  const void* __restrict__ W2,
                                                  uint4* __restrict__ wf1,
                                                  uint4* __restrict__ wf2,
                                                  const int* __restrict__ flags,
                                                  int nbN, int nbH)
{
    __shared__ int lb[256];
    int b = blockIdx.x;
    if (b < nbN) {
        int i = b * 4 + (threadIdx.x >> 6);
        if (i >= N) return;
        int lane = threadIdx.x & 63;
        u32 u;
        if (flags[0]) {
            const float* q = (const float*)x + (size_t)i * 128 + lane * 2;
            u = pack2(q[0], q[1]);
        } else u = ((const u32*)x)[(size_t)i * 64 + lane];
        xb[(size_t)i * 64 + lane] = u;
        float f0 = bflo(u), f1 = bfhi(u);
        float ss = wsum(f0 * f0 + f1 * f1);
        if (lane == 0) {
            float r = 1.0f / fmaxf(sqrtf(ss), 1e-8f);
            int a = flags[1] ? sa[2 * (size_t)i] : sa[i];
            rn[i] = a ? -r : r;            // sign encodes sensitive attr
        }
    } else if (b < nbN + nbH) {
        int t = threadIdx.x;
        lb[t] = 0;
        __syncthreads();
        int i64 = flags[1];
        size_t base = (size_t)(b - nbN) * 8192;
#pragma unroll 4
        for (int k = 0; k < 32; ++k) {
            size_t e = base + (size_t)k * 256 + t;
            if (e < (size_t)E) {
                int d = ldidx(ei, (size_t)E + e, i64);
                if ((u32)d >= (u32)N) d = 0;
                atomicAdd(&lb[d >> 8], 1);   // bucket = dst>>8 (<256, N<=65536)
            }
        }
        __syncthreads();
        int c = lb[t];
        if (c) atomicAdd(&bcnt[t], c);       // 256 counters: L2/L3-hot
    } else {
        int slot = (b - nbN - nbH) * 256 + threadIdx.x;   // 0..4095
        if (slot >= 4096) return;
        int f32w = flags[0];
        const void* W = (slot < 2048) ? W1 : W2;
        uint4* wf = (slot < 2048) ? wf1 : wf2;
        int s = slot & 2047;
        int lane = s & 63, kk = (s >> 6) & 3, ct = s >> 8;
        int q = lane >> 4, n = lane & 15;
        int col = ct * 16 + n, k0 = kk * 32 + q * 8;
        union { u16 us[8]; uint4 u4; } tmp;
#pragma unroll
        for (int j = 0; j < 8; ++j)
            tmp.us[j] = f2bf(ld1(W, (size_t)(k0 + j) * 128 + col, f32w));
        wf[s] = tmp.u4;
    }
}

// ---- bscan: 1-wave exclusive scan of 256 bucket counts -> bbase, bcur -------
// Also writes bbase[256]=E and rowp[N]=E.
__global__ void bscan_k(const int* __restrict__ bcnt, int* __restrict__ bbase,
                        int* __restrict__ bcur, int* __restrict__ rowp, int N)
{
    int lane = threadIdx.x;   // launched with 64 threads
    int carry = 0;
    for (int base = 0; base < 256; base += 64) {
        int i = base + lane;
        int v = bcnt[i];
        int sc = v;
#pragma unroll
        for (int o = 1; o < 64; o <<= 1) {
            int nv = __shfl_up(sc, o);
            if (lane >= o) sc += nv;
        }
        int excl = carry + sc - v;
        bbase[i] = excl;
        bcur[i] = excl;
        carry += __shfl(sc, 63);
    }
    if (lane == 0) { bbase[256] = carry; rowp[N] = carry; }
}

// ---- bucket: bin edges by dst>>8 into tmp (payload (src<<8)|dst&255) --------
// LDS hist gives per-edge rank; one global atomic per (block,bucket) reserves
// a dense slice -> every bucket's write cursor advances monotonically, write
// frontier = ~NB hot lines, partial pieces merge in L2 (write amp ~1).
__global__ __launch_bounds__(256) void bucket_k(const int* __restrict__ ei,
                                                int* __restrict__ bcur,
                                                u32* __restrict__ tmp,
                                                int E, int N,
                                                const int* __restrict__ flags)
{
    __shared__ int lh[256];
    __shared__ int gb[256];
    int t = threadIdx.x;
    lh[t] = 0;
    __syncthreads();
    int i64 = flags[1];
    size_t base = (size_t)blockIdx.x * 4096;
    u32 pay[16], meta[16];
#pragma unroll
    for (int k = 0; k < 16; ++k) {
        size_t e = base + (size_t)k * 256 + t;
        if (e < (size_t)E) {
            int s = ldidx(ei, e, i64);
            int d = ldidx(ei, (size_t)E + e, i64);
            if ((u32)s >= (u32)N) s = 0;
            if ((u32)d >= (u32)N) d = 0;
            int b = d >> 8;                     // < 256 since N <= 65536
            pay[k] = ((u32)s << 8) | ((u32)d & 0xFFu);
            int r = atomicAdd(&lh[b], 1);
            meta[k] = ((u32)r << 8) | (u32)b;   // rank < 4096 fits
        } else meta[k] = 0xFFFFFFFFu;
    }
    __syncthreads();
    int c = lh[t];
    gb[t] = c ? atomicAdd(&bcur[t], c) : 0;
    __syncthreads();
#pragma unroll
    for (int k = 0; k < 16; ++k) {
        if (meta[k] != 0xFFFFFFFFu) {
            int b = (int)(meta[k] & 0xFFu);
            int r = (int)(meta[k] >> 8);
            tmp[gb[b] + r] = pay[k];
        }
    }
}

// ---- scat2: per-bucket CSR finalize within a 16KB L2-resident window --------
// Block b owns nodes [b<<8,(b+1)<<8); its tmp slice & rec window tile
// [bbase[b], bbase[b+1]). Local LDS hist of 256 node counts + in-block scan
// -> coalesced rowp write; scatter via LDS cursors (no global atomics).
__global__ __launch_bounds__(256) void scat2_k(const int* __restrict__ bbase,
                                               int* __restrict__ rowp,
                                               const u32* __restrict__ tmp,
                                               u32* __restrict__ rec,
                                               int N, int E)
{
    __shared__ int lcnt[256];
    __shared__ int wtot[4];
    int b = blockIdx.x, t = threadIdx.x;
    int lane = t & 63, w = t >> 6;
    int n0 = b << 8;
    int p0 = bbase[b], p1 = bbase[b + 1];
    if (p0 < 0) p0 = 0;
    if (p1 > E) p1 = E;
    lcnt[t] = 0;
    __syncthreads();
    for (int idx = p0 + t; idx < p1; idx += 256)
        atomicAdd(&lcnt[tmp[idx] & 0xFFu], 1);
    __syncthreads();
    int v = lcnt[t];
    int sc = v;
#pragma unroll
    for (int o = 1; o < 64; o <<= 1) {
        int nv = __shfl_up(sc, o);
        if (lane >= o) sc += nv;
    }
    if (lane == 63) wtot[w] = sc;
    __syncthreads();
    int wo = 0;
#pragma unroll
    for (int k = 0; k < 4; ++k) { int s = wtot[k]; if (k < w) wo += s; }
    int excl = wo + sc - v;                 // local exclusive offset
    int node = n0 + t;
    if (node < N) rowp[node] = p0 + excl;   // coalesced CSR rowptr write
    lcnt[t] = excl;                         // reuse as scatter cursor
    __syncthreads();
    for (int idx = p0 + t; idx < p1; idx += 256) {
        u32 pay = tmp[idx];
        int r = atomicAdd(&lcnt[pay & 0xFFu], 1);   // LDS atomic
        int pos = p0 + r;
        if ((u32)pos >= (u32)E) pos = 0;
        rec[pos] = pay >> 8;                        // plain src index
    }
}

// ---- ewcsr: edge weights in CSR order + fused dinv --------------------------
// Wave per dst node; dst row held in regs (read once, sequential); only src
// rows gathered (halves gather volume vs per-edge form). 16 lanes/edge,
// 4 edges/wave in flight, 2x unroll per group; weight epilogue split across
// lanes j=0/j=1 (both hold d0,d1 after xor-reduction) -> serial section
// halved vs R15. rec[p] rewritten sequentially as (src<<16)|bf16(w). Row
// weight sum -> dv[i]=rsqrt(1+sum). sa folded into sign of rn: prod<0 <=>
// attrs differ; |prod| = rn_s*rn_d.
__global__ __launch_bounds__(256) void ewcsr_k(const u32* __restrict__ xb,
                                               const float* __restrict__ rn,
                                               const int* __restrict__ rowp,
                                               u32* __restrict__ rec,
                                               float* __restrict__ dv,
                                               int N, int E)
{
    int i = blockIdx.x * 4 + (threadIdx.x >> 6);
    if (i >= N) return;
    int lane = threadIdx.x & 63, g = lane >> 4, j = lane & 15;
    uint4 D = ((const uint4*)(xb + (size_t)i * 64))[j];   // dst row, loop-invariant
    float rni = rn[i];
    int p0 = rowp[i], p1 = rowp[i + 1];
    if (p0 < 0) p0 = 0;
    if (p1 > E) p1 = E;
    float acc = 0.0f;
    int p = p0 + g;
    for (; p + 4 < p1; p += 8) {          // 2 edges per group per iter
        int s0 = (int)rec[p];     if ((u32)s0 >= (u32)N) s0 = 0;
        int s1 = (int)rec[p + 4]; if ((u32)s1 >= (u32)N) s1 = 0;
        uint4 A0 = ((const uint4*)(xb + (size_t)s0 * 64))[j];
        uint4 A1 = ((const uint4*)(xb + (size_t)s1 * 64))[j];
        float d0 = bflo(A0.x) * bflo(D.x) + bfhi(A0.x) * bfhi(D.x)
                 + bflo(A0.y) * bflo(D.y) + bfhi(A0.y) * bfhi(D.y)
                 + bflo(A0.z) * bflo(D.z) + bfhi(A0.z) * bfhi(D.z)
                 + bflo(A0.w) * bflo(D.w) + bfhi(A0.w) * bfhi(D.w);
        float d1 = bflo(A1.x) * bflo(D.x) + bfhi(A1.x) * bfhi(D.x)
                 + bflo(A1.y) * bflo(D.y) + bfhi(A1.y) * bfhi(D.y)
                 + bflo(A1.z) * bflo(D.z) + bfhi(A1.z) * bfhi(D.z)
                 + bflo(A1.w) * bflo(D.w) + bfhi(A1.w) * bfhi(D.w);
#pragma unroll
        for (int o = 8; o > 0; o >>= 1) {
            d0 += __shfl_xor(d0, o);
            d1 += __shfl_xor(d1, o);
        }
        if (j < 2) {                       // lane 0: edge p; lane 1: edge p+4
            int ss = j ? s1 : s0;
            float dd = j ? d1 : d0;
            float pr = rn[ss] * rni;
            float w = fmaxf(dd * fabsf(pr) *
                            ((pr < 0.0f) ? 0.36787944117144233f : 1.0f), 1e-4f);
            u16 wb = f2bf(w);
            rec[p + 4 * j] = ((u32)ss << 16) | wb;
            acc += bf1(wb);
        }
    }
    if (p < p1) {                          // <=1 leftover edge per group
        int s0 = (int)rec[p]; if ((u32)s0 >= (u32)N) s0 = 0;
        uint4 A0 = ((const uint4*)(xb + (size_t)s0 * 64))[j];
        float d0 = bflo(A0.x) * bflo(D.x) + bfhi(A0.x) * bfhi(D.x)
                 + bflo(A0.y) * bflo(D.y) + bfhi(A0.y) * bfhi(D.y)
                 + bflo(A0.z) * bflo(D.z) + bfhi(A0.z) * bfhi(D.z)
                 + bflo(A0.w) * bflo(D.w) + bfhi(A0.w) * bfhi(D.w);
#pragma unroll
        for (int o = 8; o > 0; o >>= 1) d0 += __shfl_xor(d0, o);
        if (j == 0) {
            float pr0 = rn[s0] * rni;
            float w0 = fmaxf(d0 * fabsf(pr0) *
                             ((pr0 < 0.0f) ? 0.36787944117144233f : 1.0f), 1e-4f);
            u16 wb0 = f2bf(w0);
            rec[p] = ((u32)s0 << 16) | wb0;
            acc += bf1(wb0);
        }
    }
    // combine lane 0/1 of each group, then the 4 groups
    acc += __shfl_xor(acc, 1);
    acc += __shfl_xor(acc, 16);
    acc += __shfl_xor(acc, 32);
    if (lane == 0) dv[i] = 1.0f / sqrtf(1.0f + acc);
}

// ---- agg: Tb[i](bf16) = dinv_i^2*feat[i] + sum_p w_p*dinv_i*dinv_s*feat[s] --
// feat packed-bf16 rows; wave/node; rec = (src<<16)|bf16(w); unroll-8 ILP.
__global__ __launch_bounds__(256) void agg_k(const u32* __restrict__ feat,
                                             const int* __restrict__ rowp,
                                             const u32* __restrict__ rec,
                                             const float* __restrict__ dinv,
                                             u32* __restrict__ Tb, int N, int E)
{
    int i = blockIdx.x * 4 + (threadIdx.x >> 6);
    if (i >= N) return;
    int lane = threadIdx.x & 63;
    float di = dinv[i], sc = di * di;
    u32 u = feat[(size_t)i * 64 + lane];
    float a0 = bflo(u) * sc, a1 = bfhi(u) * sc;
    int p0 = rowp[i], p1 = rowp[i + 1];
    if (p0 < 0) p0 = 0;
    if (p1 > E) p1 = E;
    int p = p0;
    for (; p + 7 < p1; p += 8) {
        u32 r[8]; int s[8]; u32 v[8];
#pragma unroll
        for (int k = 0; k < 8; ++k) {
            r[k] = rec[p + k];
            s[k] = r[k] >> 16;
            if (s[k] >= N) s[k] = 0;
        }
#pragma unroll
        for (int k = 0; k < 8; ++k) v[k] = feat[(size_t)s[k] * 64 + lane];
#pragma unroll
        for (int k = 0; k < 8; ++k) {
            float w = bf1((u16)r[k]) * di * dinv[s[k]];
            a0 = fmaf(w, bflo(v[k]), a0);
            a1 = fmaf(w, bfhi(v[k]), a1);
        }
    }
    for (; p + 1 < p1; p += 2) {
        u32 r0 = rec[p], r1 = rec[p + 1];
        int s0 = r0 >> 16, s1 = r1 >> 16;
        if (s0 >= N) s0 = 0;
        if (s1 >= N) s1 = 0;
        u32 v0 = feat[(size_t)s0 * 64 + lane];
        u32 v1 = feat[(size_t)s1 * 64 + lane];
        float w0 = bf1((u16)r0) * di * dinv[s0];
        float w1 = bf1((u16)r1) * di * dinv[s1];
        a0 = fmaf(w0, bflo(v0), a0); a1 = fmaf(w0, bfhi(v0), a1);
        a0 = fmaf(w1, bflo(v1), a0); a1 = fmaf(w1, bfhi(v1), a1);
    }
    if (p < p1) {
        u32 r0 = rec[p];
        int s0 = r0 >> 16;
        if (s0 >= N) s0 = 0;
        u32 v0 = feat[(size_t)s0 * 64 + lane];
        float w0 = bf1((u16)r0) * di * dinv[s0];
        a0 = fmaf(w0, bflo(v0), a0); a1 = fmaf(w0, bfhi(v0), a1);
    }
    Tb[(size_t)i * 64 + lane] = pack2(a0, a1);
}

// ---- MFMA GEMM: out = relu(Tb@W + bias); 64 rows/block, wave = 16 rows ------
// A direct from global (4 uint4/lane); B from pre-packed wfrag (L2, coalesced).
// No LDS, no barriers. Layouts identity-proven (R4 vs R5 bit-identity).
__global__ __launch_bounds__(256) void gemm_m(const u32* __restrict__ Tb,
                                              const uint4* __restrict__ wfrag,
                                              const void* __restrict__ bias,
                                              void* __restrict__ out, int outbf,
                                              int N,
                                              const void* __restrict__ Wc,
                                              const void* __restrict__ bc,
                                              float* __restrict__ yout,
                                              const int* __restrict__ flags)
{
    int t = threadIdx.x, wave = t >> 6, lane = t & 63;
    int q = lane >> 4, n = lane & 15;
    int f32w = flags[0];
    int rowbase = blockIdx.x * 64 + wave * 16;
    int arow = rowbase + n; if (arow > N - 1) arow = N - 1;
    const uint4* ap = (const uint4*)(Tb + (size_t)arow * 64);
    short8 a[4];
#pragma unroll
    for (int kk = 0; kk < 4; ++kk) {
        uint4 av = ap[kk * 4 + q];          // row arow, k = kk*32 + q*8 .. +7
        a[kk] = *(short8*)&av;
    }
    floatx4 acc[8];
#pragma unroll
    for (int ct = 0; ct < 8; ++ct) acc[ct] = (floatx4){0.f, 0.f, 0.f, 0.f};
#pragma unroll
    for (int ct = 0; ct < 8; ++ct) {
#pragma unroll
        for (int kk = 0; kk < 4; ++kk) {
            uint4 bv = wfrag[(ct * 4 + kk) * 64 + lane];
            acc[ct] = __builtin_amdgcn_mfma_f32_16x16x32_bf16(
                a[kk], *(short8*)&bv, acc[ct], 0, 0, 0);
        }
    }
    float bcv = 0.0f;
    float part[4] = {0.f, 0.f, 0.f, 0.f};
    if (yout) bcv = ld1(bc, 0, f32w);
#pragma unroll
    for (int ct = 0; ct < 8; ++ct) {
        int col = ct * 16 + n;
        float bia = ld1(bias, col, f32w);
        float wcv = yout ? ld1(Wc, col, f32w) : 0.0f;
#pragma unroll
        for (int r = 0; r < 4; ++r) {            // D row = q*4+r, col = n
            int row = rowbase + q * 4 + r;
            float h = fmaxf(acc[ct][r] + bia, 0.0f);
            if (row < N) {
                if (outbf) ((u16*)out)[(size_t)row * 128 + col] = f2bf(h);
                else       ((float*)out)[(size_t)row * 128 + col] = h;
            }
            part[r] = fmaf(h, wcv, part[r]);
        }
    }
    if (yout) {
#pragma unroll
        for (int r = 0; r < 4; ++r) {
            float pr = part[r];
#pragma unroll
            for (int o = 8; o > 0; o >>= 1) pr += __shfl_xor(pr, o); // 16-lane grp
            int row = rowbase + q * 4 + r;
            if (n == 0 && row < N) yout[row] = pr + bcv;
        }
    }
}

extern "C" void kernel_launch(void* const* d_in, const int* in_sizes, int n_in,
                              void* d_out, int out_size, void* d_ws, size_t ws_size,
                              hipStream_t stream)
{
    const void* x  = d_in[0];
    const int* ei  = (const int*)d_in[1];
    const int* sa  = (const int*)d_in[2];
    const void* W1 = d_in[3];
    const void* b1 = d_in[4];
    const void* W2 = d_in[5];
    const void* b2 = d_in[6];
    const void* Wc = d_in[7];
    const void* bc = d_in[8];
    const int N = in_sizes[2];
    const int E = in_sizes[1] / 2;

    float* y_out = (float*)d_out;
    float* h_out = y_out + N;          // final h (written only by gemm2)
    u32*   Tbuf  = (u32*)d_in[0];      // T1b then T2b in x's buffer (x dead
                                       // after convhist; >= 12.8 MB)
    u32*   tmp   = (u32*)d_in[0];      // bucket payloads (E*4B <= 3.2 MB);
                                       // consumed by scat2 before agg reuses buf

    const int nbN = (N + 3) / 4;
    const int nbH = (E + 8191) / 8192;
    const int NB  = (N + 255) / 256;   // dst buckets (<=256 since N<=65536)

    char* p = (char*)d_ws;
    auto carve = [&](size_t bytes) { char* r = p; p += (bytes + 255) & ~(size_t)255; return r; };
    int*   flags = (int*)carve(256);
    float* rn    = (float*)carve((size_t)N * 4);      // sign-folded 1/||x||
    float* dinv  = (float*)carve((size_t)N * 4);
    int*   rowp  = (int*)carve((size_t)(N + 1) * 4);
    int*   bcnt  = (int*)carve(256 * 4);              // bucket histogram
    int*   bbase = (int*)carve(260 * 4);              // bucket bases (+total)
    int*   bcur  = (int*)carve(256 * 4);              // bucket write cursors
    uint4* wf1   = (uint4*)carve(2048 * 16);          // W1 B-fragments, 32 KB
    uint4* wf2   = (uint4*)carve(2048 * 16);          // W2 B-fragments, 32 KB
    u32*   rec   = (u32*)carve((size_t)E * 4);        // (src<<16)|bf16(w)
    u32*   xb    = (u32*)carve((size_t)N * 64 * 4);   // xb, then h1b (~16.9 MB)

    classify_k<<<1, 1024, 0, stream>>>((const u32*)x, ei, flags, bcnt);
    convhist_k<<<nbN + nbH + 16, 256, 0, stream>>>(x, xb, rn, N, ei, sa, bcnt, E,
                                                   W1, W2, wf1, wf2, flags,
                                                   nbN, nbH);
    bscan_k<<<1, 64, 0, stream>>>(bcnt, bbase, bcur, rowp, N);
    bucket_k<<<(E + 4095) / 4096, 256, 0, stream>>>(ei, bcur, tmp, E, N, flags);
    scat2_k<<<NB, 256, 0, stream>>>(bbase, rowp, tmp, rec, N, E);
    ewcsr_k<<<(N + 3) / 4, 256, 0, stream>>>(xb, rn, rowp, rec, dinv, N, E);

    // layer 1: T1b = Agg(xb) -> x buf; h1b = relu(T1b@W1+b1) bf16 -> ws (xb dead)
    agg_k<<<(N + 3) / 4, 256, 0, stream>>>(xb, rowp, rec, dinv, Tbuf, N, E);
    gemm_m<<<(N + 63) / 64, 256, 0, stream>>>(Tbuf, wf1, b1, xb, 1, N,
                                              nullptr, nullptr, nullptr, flags);
    // layer 2: T2b = Agg(h1b) -> x buf; h = relu(T2b@W2+b2) f32 -> d_out + y
    agg_k<<<(N + 3) / 4, 256, 0, stream>>>(xb, rowp, rec, dinv, Tbuf, N, E);
    gemm_m<<<(N + 63) / 64, 256, 0, stream>>>(Tbuf, wf2, b2, h_out, 0, N,
                                              Wc, bc, y_out, flags);
}